// Round 19
// baseline (178.940 us; speedup 1.0000x reference)
//
#include <hip/hip_runtime.h>
#include <hip/hip_bf16.h>
#include <cstdint>
#include <type_traits>

static constexpr int NN = 50000;   // nodes per graph
static constexpr int NE = 600000;  // edges per graph
static constexpr int NB = (NN + 255) / 256;    // 196 dst-buckets (256 nodes each)
static constexpr int CHUNK = 4096;
static constexpr int NCH = (NE + CHUNK - 1) / CHUNK;  // 147 binning chunks per graph
static constexpr int CAP = 4096;  // per-bucket staging capacity (mean 3072, ~18 sigma)

typedef __bf16 bf16;
typedef __attribute__((ext_vector_type(2))) __bf16 bf16x2;
typedef __attribute__((ext_vector_type(8))) __bf16 bf16x8;
typedef __attribute__((ext_vector_type(4))) float f32x4;

// ---------------- W prep (4 jobs) + cursor/row_off init (job 5) ----------------
__global__ __launch_bounds__(256) void k_wprep4(const float* __restrict__ WA,  // 256x128
                                                const float* __restrict__ WB,  // 128x128
                                                const float* __restrict__ WC,  // 128x64
                                                const float* __restrict__ WD,  // 128x64
                                                bf16* __restrict__ wf0,        // 2 slots of 256*128
                                                bf16* __restrict__ wf1,        // 2 slots of 128*64
                                                int* __restrict__ bucketcur,
                                                int* __restrict__ row_off) {
    int y = blockIdx.y;
    int i = blockIdx.x * 256 + threadIdx.x;
    if (y == 4) {  // init job
        if (i < 2 * NB) bucketcur[i] = i * CAP;
        if (i < 2) row_off[i * (NN + 1) + NN] = NE;
        return;
    }
    const float* W = (y == 0) ? WA : (y == 1) ? WB : (y == 2) ? WC : WD;
    bf16* wf = (y == 0) ? wf0 : (y == 1) ? wf0 + 256 * 128 : (y == 2) ? wf1 : wf1 + 128 * 64;
    int K = (y == 0) ? 256 : 128;
    int F = (y <= 1) ? 128 : 64;
    if (i < K * F) {
        int k = i / F, n = i % F;
        wf[((size_t)(k >> 3) * F + n) * 8 + (k & 7)] = (bf16)W[i];
    }
}

// ---------------- bf16 MFMA GEMM body ----------------
// Fragment maps (16x16x32): A: m=l&15,k=(l>>4)*8+j ; B: n=l&15,k=(l>>4)*8+j ;
// D: n=l&15, m=(l>>4)*4+reg.
template <int K, int F, typename AT>
__device__ __forceinline__ void gemm_body(const AT* __restrict__ X,
                                          const bf16* __restrict__ wf,
                                          bf16* __restrict__ H, int n, int bx) {
    constexpr int NT = F / 16;
    int wave = threadIdx.x >> 6;
    int lane = threadIdx.x & 63;
    int lm = lane & 15;
    int lk = lane >> 4;
    int r0 = bx * 64 + wave * 16;

    int arow = r0 + lm;
    if (arow >= n) arow = n - 1;  // clamp (stores are guarded)
    const AT* xrow = X + (size_t)arow * K;

    f32x4 acc[NT] = {};

    for (int k0 = 0; k0 < K; k0 += 32) {
        bf16x8 af;
        if constexpr (std::is_same_v<AT, float>) {
            f32x4 a0 = *reinterpret_cast<const f32x4*>(xrow + k0 + lk * 8);
            f32x4 a1 = *reinterpret_cast<const f32x4*>(xrow + k0 + lk * 8 + 4);
            af[0] = (bf16)a0.x; af[1] = (bf16)a0.y; af[2] = (bf16)a0.z; af[3] = (bf16)a0.w;
            af[4] = (bf16)a1.x; af[5] = (bf16)a1.y; af[6] = (bf16)a1.z; af[7] = (bf16)a1.w;
        } else {
            af = *reinterpret_cast<const bf16x8*>(xrow + k0 + lk * 8);
        }
        const bf16* wbase = wf + ((size_t)(k0 / 8 + lk) * F) * 8;
        #pragma unroll
        for (int t = 0; t < NT; ++t) {
            bf16x8 bfg = *reinterpret_cast<const bf16x8*>(wbase + (t * 16 + lm) * 8);
            acc[t] = __builtin_amdgcn_mfma_f32_16x16x32_bf16(af, bfg, acc[t], 0, 0, 0);
        }
    }

    #pragma unroll
    for (int t = 0; t < NT; ++t) {
        #pragma unroll
        for (int i = 0; i < 4; ++i) {
            int gr = r0 + lk * 4 + i;
            if (gr < n) H[(size_t)gr * F + t * 16 + lm] = (bf16)acc[t][i];
        }
    }
}

static constexpr int GB = (NN + 63) / 64;  // 782 gemm blocks per graph

// ---------------- mega kernel: binA-sorted (blocks [0,2NCH)) || gemm_l1 (after) ----------
// LDS footprint cut to ~11.5 KB (16-bit chunk-local sort indices instead of int2 edges)
// so ALL mega blocks (incl. gemm) reach the 8-blocks/CU wave cap.
__global__ __launch_bounds__(256) void k_mega(const float* __restrict__ x1,
                                              const float* __restrict__ x2,
                                              const bf16* __restrict__ wf0,
                                              bf16* __restrict__ h,
                                              const int* __restrict__ srcA,
                                              const int* __restrict__ dstA,
                                              const int* __restrict__ srcB,
                                              const int* __restrict__ dstB,
                                              int* __restrict__ bucketcur,
                                              int2* __restrict__ stg) {
    __shared__ unsigned short sidx[CHUNK];  // 8 KB: bucket-sorted chunk-local edge ids
    __shared__ int s[256];
    __shared__ int cnt[NB];
    __shared__ int lbase[NB];
    __shared__ int ibase[NB];
    int bx = blockIdx.x;
    if (bx >= 2 * NCH) {
        // ---- gemm_l1 job ----
        int gx = bx - 2 * NCH;
        if (gx < GB)
            gemm_body<256, 128, float>(x1, wf0, h, NN, gx);
        else
            gemm_body<128, 128, float>(x2, wf0 + 256 * 128, h + (size_t)NN * 128, NN, gx - GB);
        return;
    }
    // ---- binA job ----
    int g = (bx >= NCH);
    int chunk = bx - g * NCH;
    const int* src = g ? srcB : srcA;
    const int* dst = g ? dstB : dstA;
    int tid = threadIdx.x;
    int c0 = chunk * CHUNK;
    int total = min(CHUNK, NE - c0);

    if (tid < NB) cnt[tid] = 0;
    __syncthreads();
    #pragma unroll
    for (int it = 0; it < CHUNK / 256; ++it) {
        int e = c0 + it * 256 + tid;
        if (e < NE) atomicAdd(&cnt[dst[e] >> 8], 1);
    }
    __syncthreads();
    // exclusive scan of cnt -> lbase (LDS run offsets); reserve global ranges -> ibase
    int v = (tid < NB) ? cnt[tid] : 0;
    s[tid] = v;
    __syncthreads();
    for (int off = 1; off < 256; off <<= 1) {
        int t = (tid >= off) ? s[tid - off] : 0;
        __syncthreads();
        s[tid] += t;
        __syncthreads();
    }
    int incl = s[tid];
    __syncthreads();
    if (tid < NB) {
        lbase[tid] = incl - v;
        ibase[tid] = v ? atomicAdd(&bucketcur[g * NB + tid], v) : 0;
        cnt[tid] = 0;
    }
    __syncthreads();
    // scatter chunk-local edge ids into LDS in bucket-sorted order
    #pragma unroll
    for (int it = 0; it < CHUNK / 256; ++it) {
        int le = it * 256 + tid;
        int e = c0 + le;
        if (e < NE) {
            int b = dst[e] >> 8;
            int p = atomicAdd(&cnt[b], 1);
            sidx[lbase[b] + p] = (unsigned short)le;
        }
    }
    __syncthreads();
    // linear write-out: consecutive threads -> consecutive stg addresses per bucket run
    // (src/dst re-read is L2-hot: 3rd touch of the same cache lines)
    for (int p = tid; p < total; p += 256) {
        int e = c0 + sidx[p];
        int sv = src[e], d = dst[e];
        int b = d >> 8;
        stg[(size_t)ibase[b] + (p - lbase[b])] = make_int2(sv, d);
    }
}

// ---------------- binB1: inline bucket-base scan + per-bucket node histogram ->
//                  row_off slice + dinv ----------------
__global__ __launch_bounds__(256) void k_binB1(const int2* __restrict__ stg,
                                               const int* __restrict__ bucketcur,
                                               int* __restrict__ row_off,
                                               float* __restrict__ dinv) {
    __shared__ int cnt[256];
    __shared__ int s[256];
    __shared__ int bb[256];
    int g = blockIdx.y;
    int b = blockIdx.x;
    int B = g * NB + b;
    int tid = threadIdx.x;

    // bucket-base: exclusive scan over this graph's 196 bucket counts
    int cv = (tid < NB) ? bucketcur[g * NB + tid] - (g * NB + tid) * CAP : 0;
    s[tid] = cv;
    __syncthreads();
    for (int off = 1; off < 256; off <<= 1) {
        int t = (tid >= off) ? s[tid - off] : 0;
        __syncthreads();
        s[tid] += t;
        __syncthreads();
    }
    if (tid < NB) bb[tid] = s[tid] - cv;
    cnt[tid] = 0;
    __syncthreads();
    int base = bb[b];

    int node0 = b << 8;
    int nnod = min(256, NN - node0);
    int count = bucketcur[B] - B * CAP;
    const int2* s0 = stg + (size_t)B * CAP;
    for (int j = tid; j < count; j += 256)
        atomicAdd(&cnt[s0[j].y - node0], 1);
    __syncthreads();
    int v = cnt[tid];
    s[tid] = v;
    __syncthreads();
    for (int off = 1; off < 256; off <<= 1) {
        int t = (tid >= off) ? s[tid - off] : 0;
        __syncthreads();
        s[tid] += t;
        __syncthreads();
    }
    if (tid < nnod) {
        row_off[g * (NN + 1) + node0 + tid] = base + s[tid] - v;
        dinv[(size_t)g * NN + node0 + tid] = rsqrtf((float)v + 1.0f);
    }
}

// ---------------- binB2: bucket region -> exact CSR position (LDS cursors) + coef ----------
// pair.x = src << 8 (byte offset of the 256B h-row).
__global__ __launch_bounds__(256) void k_binB2(const int2* __restrict__ stg,
                                               const int* __restrict__ bucketcur,
                                               const int* __restrict__ row_off,
                                               const float* __restrict__ dinv,
                                               int2* __restrict__ pair) {
    __shared__ int lcur[256];
    __shared__ float ldv[256];
    int g = blockIdx.y;
    int b = blockIdx.x;
    int B = g * NB + b;
    int tid = threadIdx.x;
    int node0 = b << 8;
    int nnod = min(256, NN - node0);
    const int* ro = row_off + g * (NN + 1);
    if (tid < nnod) {
        lcur[tid] = ro[node0 + tid];
        ldv[tid] = dinv[(size_t)g * NN + node0 + tid];
    }
    __syncthreads();
    int count = bucketcur[B] - B * CAP;
    const int2* s0 = stg + (size_t)B * CAP;
    for (int j = tid; j < count; j += 256) {
        int2 sd = s0[j];
        int rel = sd.y - node0;
        int pos = atomicAdd(&lcur[rel], 1);
        float cf = dinv[(size_t)g * NN + sd.x] * ldv[rel];
        pair[(size_t)g * NE + pos] = make_int2(sd.x << 8, __float_as_int(cf));
    }
}

// layer 2: both graphs K=128 -> F=64, A bf16
__global__ __launch_bounds__(256) void gemm_l2(const bf16* __restrict__ a,
                                               const bf16* __restrict__ wf1,
                                               bf16* __restrict__ h2) {
    int bx = blockIdx.x;
    int g = (bx >= GB);
    gemm_body<128, 64, bf16>(a + (size_t)g * NN * 128, wf1 + g * 128 * 64,
                             h2 + (size_t)g * NN * 64, NN, bx - g * GB);
}

// ---------------- aggregation F=128: wave per node, int4 pair loads, 8-edge unroll --------
// pair.x is the h-row BYTE offset (src*256); lane adds its feature-byte offset directly.
__global__ __launch_bounds__(256) void agg128_2(const bf16* __restrict__ hb,
                                                const int* __restrict__ row_off,
                                                const int2* __restrict__ pairb,
                                                const float* __restrict__ dinv,
                                                const float* __restrict__ biasA,
                                                const float* __restrict__ biasB,
                                                bf16* __restrict__ ab) {
    int wid = blockIdx.x * 4 + (threadIdx.x >> 6);
    if (wid >= 2 * NN) return;
    int g = (wid >= NN);
    int node = wid - g * NN;
    int lane = threadIdx.x & 63;

    const bf16* h = hb + (size_t)g * NN * 128;
    const char* hB = reinterpret_cast<const char*>(h);
    const int2* pair = pairb + (size_t)g * NE;
    const int* ro = row_off + g * (NN + 1);
    const float* bias = g ? biasB : biasA;

    int f = lane * 2;
    int fb = lane * 4;  // byte offset of this lane's 2 features
    float di = dinv[g * NN + node];
    int beg = ro[node];
    int end = ro[node + 1];

    float a0 = 0.f, a1 = 0.f;

    auto edge1 = [&](int2 p) {
        float c = __int_as_float(p.y);
        bf16x2 v = *reinterpret_cast<const bf16x2*>(hB + (unsigned)p.x + fb);
        a0 = fmaf((float)v[0], c, a0); a1 = fmaf((float)v[1], c, a1);
    };
    auto edge2 = [&](int4 q) {  // two edges in one aligned 16B load
        float cA = __int_as_float(q.y), cB = __int_as_float(q.w);
        bf16x2 vA = *reinterpret_cast<const bf16x2*>(hB + (unsigned)q.x + fb);
        bf16x2 vB = *reinterpret_cast<const bf16x2*>(hB + (unsigned)q.z + fb);
        a0 = fmaf((float)vA[0], cA, a0); a1 = fmaf((float)vA[1], cA, a1);
        a0 = fmaf((float)vB[0], cB, a0); a1 = fmaf((float)vB[1], cB, a1);
    };

    int j = beg;
    if ((j & 1) && j < end) { edge1(pair[j]); ++j; }  // align to 16B
    for (; j + 7 < end; j += 8) {
        int4 q0 = *reinterpret_cast<const int4*>(&pair[j]);
        int4 q1 = *reinterpret_cast<const int4*>(&pair[j + 2]);
        int4 q2 = *reinterpret_cast<const int4*>(&pair[j + 4]);
        int4 q3 = *reinterpret_cast<const int4*>(&pair[j + 6]);
        edge2(q0); edge2(q1); edge2(q2); edge2(q3);
    }
    for (; j + 1 < end; j += 2) {
        int4 q = *reinterpret_cast<const int4*>(&pair[j]);
        edge2(q);
    }
    if (j < end) edge1(pair[j]);

    bf16x2 hv = *reinterpret_cast<const bf16x2*>(&h[(size_t)node * 128 + f]);
    float sc = di * di;
    a0 = fmaf((float)hv[0], sc, a0) + bias[f];
    a1 = fmaf((float)hv[1], sc, a1) + bias[f + 1];
    a0 = fmaxf(a0, 0.f);
    a1 = fmaxf(a1, 0.f);

    bf16x2 r;
    r[0] = (bf16)a0; r[1] = (bf16)a1;
    *reinterpret_cast<bf16x2*>(&ab[((size_t)g * NN + node) * 128 + f]) = r;
}

// ---------------- aggregation F=64: wave per node (2 edges in parallel, 8-unrolled) -------
// pair.x>>1 = 128B-row byte offset into h2.
__global__ __launch_bounds__(256) void agg64_2(const bf16* __restrict__ h2b,
                                               const int* __restrict__ row_off,
                                               const int2* __restrict__ pairb,
                                               const float* __restrict__ dinv,
                                               const float* __restrict__ biasA,
                                               const float* __restrict__ biasB,
                                               float* __restrict__ outb) {
    int wid = blockIdx.x * 4 + (threadIdx.x >> 6);
    if (wid >= 2 * NN) return;
    int g = (wid >= NN);
    int node = wid - g * NN;
    int lane = threadIdx.x & 63;

    const bf16* h = h2b + (size_t)g * NN * 64;
    const char* hB = reinterpret_cast<const char*>(h);
    const int2* pair = pairb + (size_t)g * NE;
    const int* ro = row_off + g * (NN + 1);
    const float* bias = g ? biasB : biasA;
    float* out = outb + (size_t)g * NN * 64;

    int half = lane >> 5;
    int f = (lane & 31) * 2;
    int fb = (lane & 31) * 4;
    float di = dinv[(size_t)g * NN + node];
    int beg = ro[node];
    int end = ro[node + 1];

    float a0 = 0.f, a1 = 0.f;

    auto edge = [&](int2 p) {
        float c = __int_as_float(p.y);
        bf16x2 v = *reinterpret_cast<const bf16x2*>(hB + (((unsigned)p.x) >> 1) + fb);
        a0 = fmaf((float)v[0], c, a0); a1 = fmaf((float)v[1], c, a1);
    };

    int j = beg;
    for (; j + 7 < end; j += 8) {
        int2 p0 = pair[j + half], p1 = pair[j + 2 + half];
        int2 p2 = pair[j + 4 + half], p3 = pair[j + 6 + half];
        edge(p0); edge(p1); edge(p2); edge(p3);
    }
    for (; j + 1 < end; j += 2) edge(pair[j + half]);
    if (j < end && half == 0) edge(pair[j]);

    a0 += __shfl_xor(a0, 32);
    a1 += __shfl_xor(a1, 32);

    bf16x2 hv = *reinterpret_cast<const bf16x2*>(&h[(size_t)node * 64 + f]);
    float sc = di * di;
    a0 = fmaf((float)hv[0], sc, a0) + bias[f];
    a1 = fmaf((float)hv[1], sc, a1) + bias[f + 1];

    if (half == 0) {
        out[(size_t)node * 64 + f] = a0;
        out[(size_t)node * 64 + f + 1] = a1;
    }
}

extern "C" void kernel_launch(void* const* d_in, const int* in_sizes, int n_in,
                              void* d_out, int out_size, void* d_ws, size_t ws_size,
                              hipStream_t stream) {
    const float* x1 = (const float*)d_in[0];
    const int* ei1 = (const int*)d_in[1];
    const float* x2 = (const float*)d_in[2];
    const int* ei2 = (const int*)d_in[3];
    const float* W1_0 = (const float*)d_in[4];
    const float* b1_0 = (const float*)d_in[5];
    const float* W1_1 = (const float*)d_in[6];
    const float* b1_1 = (const float*)d_in[7];
    const float* W2_0 = (const float*)d_in[8];
    const float* b2_0 = (const float*)d_in[9];
    const float* W2_1 = (const float*)d_in[10];
    const float* b2_1 = (const float*)d_in[11];

    float* out = (float*)d_out;  // [2][NN][64] concatenated

    char* ws = (char*)d_ws;
    size_t off = 0;
    auto alloc = [&](size_t bytes) {
        size_t o = off;
        off = (off + bytes + 255) & ~(size_t)255;
        return o;
    };
    // h: live mega -> agg128. region2: stg (dead after binB2) then h2 (written by gemm_l2).
    bf16* h = (bf16*)(ws + alloc((size_t)2 * NN * 128 * 2));       // 25.6 MB
    size_t r2 = (size_t)2 * NB * CAP * 8;                          // 12.85 MB (>= h2's 12.8)
    char* region2 = ws + alloc(r2);
    int2* stg = (int2*)region2;
    bf16* h2 = (bf16*)region2;
    bf16* a = (bf16*)(ws + alloc((size_t)2 * NN * 128 * 2));       // 25.6 MB
    int2* pair = (int2*)(ws + alloc((size_t)2 * NE * 8));          // 9.6 MB
    int* row_off = (int*)(ws + alloc((size_t)2 * (NN + 1) * 4));
    float* dinv = (float*)(ws + alloc((size_t)2 * NN * 4));
    int* bucketcur = (int*)(ws + alloc((size_t)2 * NB * 4));
    bf16* wf0 = (bf16*)(ws + alloc((size_t)2 * 256 * 128 * 2));
    bf16* wf1 = (bf16*)(ws + alloc((size_t)2 * 128 * 64 * 2));

    const int* srcA = ei1, *dstA = ei1 + NE;
    const int* srcB = ei2, *dstB = ei2 + NE;

    k_wprep4<<<dim3(128, 5), 256, 0, stream>>>(W1_0, W2_0, W1_1, W2_1, wf0, wf1,
                                               bucketcur, row_off);
    k_mega<<<2 * NCH + 2 * GB, 256, 0, stream>>>(x1, x2, wf0, h,
                                                 srcA, dstA, srcB, dstB, bucketcur, stg);
    k_binB1<<<dim3(NB, 2), 256, 0, stream>>>(stg, bucketcur, row_off, dinv);
    k_binB2<<<dim3(NB, 2), 256, 0, stream>>>(stg, bucketcur, row_off, dinv, pair);

    agg128_2<<<(2 * NN + 3) / 4, 256, 0, stream>>>(h, row_off, pair, dinv, b1_0, b2_0, a);
    gemm_l2<<<2 * GB, 256, 0, stream>>>(a, wf1, h2);
    agg64_2<<<(2 * NN + 3) / 4, 256, 0, stream>>>(h2, row_off, pair, dinv, b1_1, b2_1, out);
}

// Round 20
// 172.341 us; speedup vs baseline: 1.0383x; 1.0383x over previous
//
#include <hip/hip_runtime.h>
#include <hip/hip_bf16.h>
#include <cstdint>
#include <type_traits>

static constexpr int NN = 50000;   // nodes per graph
static constexpr int NE = 600000;  // edges per graph
static constexpr int NB = (NN + 255) / 256;    // 196 dst-buckets (256 nodes each)
static constexpr int CHUNK = 4096;
static constexpr int NCH = (NE + CHUNK - 1) / CHUNK;  // 147 binning chunks per graph
static constexpr int CAP = 4096;  // per-bucket staging capacity (mean 3072, ~18 sigma)

typedef __bf16 bf16;
typedef __attribute__((ext_vector_type(2))) __bf16 bf16x2;
typedef __attribute__((ext_vector_type(8))) __bf16 bf16x8;
typedef __attribute__((ext_vector_type(4))) float f32x4;

// ---------------- W prep (4 jobs) + cursor/row_off init (job 5) ----------------
__global__ __launch_bounds__(256) void k_wprep4(const float* __restrict__ WA,  // 256x128
                                                const float* __restrict__ WB,  // 128x128
                                                const float* __restrict__ WC,  // 128x64
                                                const float* __restrict__ WD,  // 128x64
                                                bf16* __restrict__ wf0,        // 2 slots of 256*128
                                                bf16* __restrict__ wf1,        // 2 slots of 128*64
                                                int* __restrict__ bucketcur,
                                                int* __restrict__ row_off) {
    int y = blockIdx.y;
    int i = blockIdx.x * 256 + threadIdx.x;
    if (y == 4) {  // init job
        if (i < 2 * NB) bucketcur[i] = i * CAP;
        if (i < 2) row_off[i * (NN + 1) + NN] = NE;
        return;
    }
    const float* W = (y == 0) ? WA : (y == 1) ? WB : (y == 2) ? WC : WD;
    bf16* wf = (y == 0) ? wf0 : (y == 1) ? wf0 + 256 * 128 : (y == 2) ? wf1 : wf1 + 128 * 64;
    int K = (y == 0) ? 256 : 128;
    int F = (y <= 1) ? 128 : 64;
    if (i < K * F) {
        int k = i / F, n = i % F;
        wf[((size_t)(k >> 3) * F + n) * 8 + (k & 7)] = (bf16)W[i];
    }
}

// ---------------- bf16 MFMA GEMM body ----------------
// Fragment maps (16x16x32): A: m=l&15,k=(l>>4)*8+j ; B: n=l&15,k=(l>>4)*8+j ;
// D: n=l&15, m=(l>>4)*4+reg.
template <int K, int F, typename AT>
__device__ __forceinline__ void gemm_body(const AT* __restrict__ X,
                                          const bf16* __restrict__ wf,
                                          bf16* __restrict__ H, int n, int bx) {
    constexpr int NT = F / 16;
    int wave = threadIdx.x >> 6;
    int lane = threadIdx.x & 63;
    int lm = lane & 15;
    int lk = lane >> 4;
    int r0 = bx * 64 + wave * 16;

    int arow = r0 + lm;
    if (arow >= n) arow = n - 1;  // clamp (stores are guarded)
    const AT* xrow = X + (size_t)arow * K;

    f32x4 acc[NT] = {};

    for (int k0 = 0; k0 < K; k0 += 32) {
        bf16x8 af;
        if constexpr (std::is_same_v<AT, float>) {
            f32x4 a0 = *reinterpret_cast<const f32x4*>(xrow + k0 + lk * 8);
            f32x4 a1 = *reinterpret_cast<const f32x4*>(xrow + k0 + lk * 8 + 4);
            af[0] = (bf16)a0.x; af[1] = (bf16)a0.y; af[2] = (bf16)a0.z; af[3] = (bf16)a0.w;
            af[4] = (bf16)a1.x; af[5] = (bf16)a1.y; af[6] = (bf16)a1.z; af[7] = (bf16)a1.w;
        } else {
            af = *reinterpret_cast<const bf16x8*>(xrow + k0 + lk * 8);
        }
        const bf16* wbase = wf + ((size_t)(k0 / 8 + lk) * F) * 8;
        #pragma unroll
        for (int t = 0; t < NT; ++t) {
            bf16x8 bfg = *reinterpret_cast<const bf16x8*>(wbase + (t * 16 + lm) * 8);
            acc[t] = __builtin_amdgcn_mfma_f32_16x16x32_bf16(af, bfg, acc[t], 0, 0, 0);
        }
    }

    #pragma unroll
    for (int t = 0; t < NT; ++t) {
        #pragma unroll
        for (int i = 0; i < 4; ++i) {
            int gr = r0 + lk * 4 + i;
            if (gr < n) H[(size_t)gr * F + t * 16 + lm] = (bf16)acc[t][i];
        }
    }
}

static constexpr int GB = (NN + 63) / 64;  // 782 gemm blocks per graph

// ---------------- mega kernel: binA-sorted (blocks [0,2NCH)) || gemm_l1 (after) ----------
__global__ __launch_bounds__(256) void k_mega(const float* __restrict__ x1,
                                              const float* __restrict__ x2,
                                              const bf16* __restrict__ wf0,
                                              bf16* __restrict__ h,
                                              const int* __restrict__ srcA,
                                              const int* __restrict__ dstA,
                                              const int* __restrict__ srcB,
                                              const int* __restrict__ dstB,
                                              int* __restrict__ bucketcur,
                                              int2* __restrict__ stg) {
    __shared__ int2 sorted[CHUNK];   // 32 KB; first 1 KB doubles as scan temp
    __shared__ int cnt[NB];
    __shared__ int lbase[NB];
    __shared__ int ibase[NB];
    int bx = blockIdx.x;
    if (bx >= 2 * NCH) {
        // ---- gemm_l1 job ----
        int gx = bx - 2 * NCH;
        if (gx < GB)
            gemm_body<256, 128, float>(x1, wf0, h, NN, gx);
        else
            gemm_body<128, 128, float>(x2, wf0 + 256 * 128, h + (size_t)NN * 128, NN, gx - GB);
        return;
    }
    // ---- binA job ----
    int g = (bx >= NCH);
    int chunk = bx - g * NCH;
    const int* src = g ? srcB : srcA;
    const int* dst = g ? dstB : dstA;
    int tid = threadIdx.x;
    int c0 = chunk * CHUNK;
    int total = min(CHUNK, NE - c0);

    if (tid < NB) cnt[tid] = 0;
    __syncthreads();
    #pragma unroll
    for (int it = 0; it < CHUNK / 256; ++it) {
        int e = c0 + it * 256 + tid;
        if (e < NE) atomicAdd(&cnt[dst[e] >> 8], 1);
    }
    __syncthreads();
    // exclusive scan of cnt -> lbase (LDS run offsets); reserve global ranges -> ibase
    int* s = reinterpret_cast<int*>(sorted);  // safe: overwritten after the next barrier
    int v = (tid < NB) ? cnt[tid] : 0;
    s[tid] = v;
    __syncthreads();
    for (int off = 1; off < 256; off <<= 1) {
        int t = (tid >= off) ? s[tid - off] : 0;
        __syncthreads();
        s[tid] += t;
        __syncthreads();
    }
    int incl = s[tid];
    __syncthreads();
    if (tid < NB) {
        lbase[tid] = incl - v;
        ibase[tid] = v ? atomicAdd(&bucketcur[g * NB + tid], v) : 0;
        cnt[tid] = 0;
    }
    __syncthreads();
    // scatter chunk edges into LDS in bucket-sorted order
    #pragma unroll
    for (int it = 0; it < CHUNK / 256; ++it) {
        int e = c0 + it * 256 + tid;
        if (e < NE) {
            int sv = src[e], d = dst[e];
            int b = d >> 8;
            int p = atomicAdd(&cnt[b], 1);
            sorted[lbase[b] + p] = make_int2(sv, d);
        }
    }
    __syncthreads();
    // linear write-out: consecutive threads -> consecutive stg addresses per bucket run
    for (int p = tid; p < total; p += 256) {
        int2 sd = sorted[p];
        int b = sd.y >> 8;
        stg[(size_t)ibase[b] + (p - lbase[b])] = sd;
    }
}

// ---------------- binB1: inline bucket-base scan + per-bucket node histogram ->
//                  row_off slice + dinv ----------------
__global__ __launch_bounds__(256) void k_binB1(const int2* __restrict__ stg,
                                               const int* __restrict__ bucketcur,
                                               int* __restrict__ row_off,
                                               float* __restrict__ dinv) {
    __shared__ int cnt[256];
    __shared__ int s[256];
    __shared__ int bb[256];
    int g = blockIdx.y;
    int b = blockIdx.x;
    int B = g * NB + b;
    int tid = threadIdx.x;

    // bucket-base: exclusive scan over this graph's 196 bucket counts
    int cv = (tid < NB) ? bucketcur[g * NB + tid] - (g * NB + tid) * CAP : 0;
    s[tid] = cv;
    __syncthreads();
    for (int off = 1; off < 256; off <<= 1) {
        int t = (tid >= off) ? s[tid - off] : 0;
        __syncthreads();
        s[tid] += t;
        __syncthreads();
    }
    if (tid < NB) bb[tid] = s[tid] - cv;
    cnt[tid] = 0;
    __syncthreads();
    int base = bb[b];

    int node0 = b << 8;
    int nnod = min(256, NN - node0);
    int count = bucketcur[B] - B * CAP;
    const int2* s0 = stg + (size_t)B * CAP;
    for (int j = tid; j < count; j += 256)
        atomicAdd(&cnt[s0[j].y - node0], 1);
    __syncthreads();
    int v = cnt[tid];
    s[tid] = v;
    __syncthreads();
    for (int off = 1; off < 256; off <<= 1) {
        int t = (tid >= off) ? s[tid - off] : 0;
        __syncthreads();
        s[tid] += t;
        __syncthreads();
    }
    if (tid < nnod) {
        row_off[g * (NN + 1) + node0 + tid] = base + s[tid] - v;
        dinv[(size_t)g * NN + node0 + tid] = rsqrtf((float)v + 1.0f);
    }
}

// ---------------- binB2: bucket region -> exact CSR position (LDS cursors) + coef ----------
// pair.x = src << 8 (byte offset of the 256B h-row).
__global__ __launch_bounds__(256) void k_binB2(const int2* __restrict__ stg,
                                               const int* __restrict__ bucketcur,
                                               const int* __restrict__ row_off,
                                               const float* __restrict__ dinv,
                                               int2* __restrict__ pair) {
    __shared__ int lcur[256];
    __shared__ float ldv[256];
    int g = blockIdx.y;
    int b = blockIdx.x;
    int B = g * NB + b;
    int tid = threadIdx.x;
    int node0 = b << 8;
    int nnod = min(256, NN - node0);
    const int* ro = row_off + g * (NN + 1);
    if (tid < nnod) {
        lcur[tid] = ro[node0 + tid];
        ldv[tid] = dinv[(size_t)g * NN + node0 + tid];
    }
    __syncthreads();
    int count = bucketcur[B] - B * CAP;
    const int2* s0 = stg + (size_t)B * CAP;
    for (int j = tid; j < count; j += 256) {
        int2 sd = s0[j];
        int rel = sd.y - node0;
        int pos = atomicAdd(&lcur[rel], 1);
        float cf = dinv[(size_t)g * NN + sd.x] * ldv[rel];
        pair[(size_t)g * NE + pos] = make_int2(sd.x << 8, __float_as_int(cf));
    }
}

// layer 2: both graphs K=128 -> F=64, A bf16
__global__ __launch_bounds__(256) void gemm_l2(const bf16* __restrict__ a,
                                               const bf16* __restrict__ wf1,
                                               bf16* __restrict__ h2) {
    int bx = blockIdx.x;
    int g = (bx >= GB);
    gemm_body<128, 64, bf16>(a + (size_t)g * NN * 128, wf1 + g * 128 * 64,
                             h2 + (size_t)g * NN * 64, NN, bx - g * GB);
}

// XCD-partitioned block->node map for the agg kernels: blocks round-robin XCDs
// (XCD ~ blockIdx%8), so route XCDs 0-3 to graph 0 and XCDs 4-7 to graph 1.
// Each XCD's L2 then only caches its own graph's h (12.8 MB vs 25.6 MB hot set).
// Pure permutation: correctness independent of the actual XCD mapping.
__device__ __forceinline__ void agg_map(int bx, int& g, int& node0) {
    g = (bx & 7) >= 4;
    int i = (bx >> 3) * 4 + (bx & 3);  // [0, 12500) per graph
    node0 = i * 4;                     // 4 nodes (waves) per block
}

// ---------------- aggregation F=128: wave per node, int4 pair loads, 8-edge unroll --------
// pair.x is the h-row BYTE offset (src*256); lane adds its feature-byte offset directly.
__global__ __launch_bounds__(256) void agg128_2(const bf16* __restrict__ hb,
                                                const int* __restrict__ row_off,
                                                const int2* __restrict__ pairb,
                                                const float* __restrict__ dinv,
                                                const float* __restrict__ biasA,
                                                const float* __restrict__ biasB,
                                                bf16* __restrict__ ab) {
    int g, node0;
    agg_map(blockIdx.x, g, node0);
    int node = node0 + (threadIdx.x >> 6);
    int lane = threadIdx.x & 63;

    const bf16* h = hb + (size_t)g * NN * 128;
    const char* hB = reinterpret_cast<const char*>(h);
    const int2* pair = pairb + (size_t)g * NE;
    const int* ro = row_off + g * (NN + 1);
    const float* bias = g ? biasB : biasA;

    int f = lane * 2;
    int fb = lane * 4;  // byte offset of this lane's 2 features
    float di = dinv[(size_t)g * NN + node];
    int beg = ro[node];
    int end = ro[node + 1];

    float a0 = 0.f, a1 = 0.f;

    auto edge1 = [&](int2 p) {
        float c = __int_as_float(p.y);
        bf16x2 v = *reinterpret_cast<const bf16x2*>(hB + (unsigned)p.x + fb);
        a0 = fmaf((float)v[0], c, a0); a1 = fmaf((float)v[1], c, a1);
    };
    auto edge2 = [&](int4 q) {  // two edges in one aligned 16B load
        float cA = __int_as_float(q.y), cB = __int_as_float(q.w);
        bf16x2 vA = *reinterpret_cast<const bf16x2*>(hB + (unsigned)q.x + fb);
        bf16x2 vB = *reinterpret_cast<const bf16x2*>(hB + (unsigned)q.z + fb);
        a0 = fmaf((float)vA[0], cA, a0); a1 = fmaf((float)vA[1], cA, a1);
        a0 = fmaf((float)vB[0], cB, a0); a1 = fmaf((float)vB[1], cB, a1);
    };

    int j = beg;
    if ((j & 1) && j < end) { edge1(pair[j]); ++j; }  // align to 16B
    for (; j + 7 < end; j += 8) {
        int4 q0 = *reinterpret_cast<const int4*>(&pair[j]);
        int4 q1 = *reinterpret_cast<const int4*>(&pair[j + 2]);
        int4 q2 = *reinterpret_cast<const int4*>(&pair[j + 4]);
        int4 q3 = *reinterpret_cast<const int4*>(&pair[j + 6]);
        edge2(q0); edge2(q1); edge2(q2); edge2(q3);
    }
    for (; j + 1 < end; j += 2) {
        int4 q = *reinterpret_cast<const int4*>(&pair[j]);
        edge2(q);
    }
    if (j < end) edge1(pair[j]);

    bf16x2 hv = *reinterpret_cast<const bf16x2*>(&h[(size_t)node * 128 + f]);
    float sc = di * di;
    a0 = fmaf((float)hv[0], sc, a0) + bias[f];
    a1 = fmaf((float)hv[1], sc, a1) + bias[f + 1];
    a0 = fmaxf(a0, 0.f);
    a1 = fmaxf(a1, 0.f);

    bf16x2 r;
    r[0] = (bf16)a0; r[1] = (bf16)a1;
    *reinterpret_cast<bf16x2*>(&ab[((size_t)g * NN + node) * 128 + f]) = r;
}

// ---------------- aggregation F=64: wave per node (2 edges in parallel, 8-unrolled) -------
// pair.x>>1 = 128B-row byte offset into h2.
__global__ __launch_bounds__(256) void agg64_2(const bf16* __restrict__ h2b,
                                               const int* __restrict__ row_off,
                                               const int2* __restrict__ pairb,
                                               const float* __restrict__ dinv,
                                               const float* __restrict__ biasA,
                                               const float* __restrict__ biasB,
                                               float* __restrict__ outb) {
    int g, node0;
    agg_map(blockIdx.x, g, node0);
    int node = node0 + (threadIdx.x >> 6);
    int lane = threadIdx.x & 63;

    const bf16* h = h2b + (size_t)g * NN * 64;
    const char* hB = reinterpret_cast<const char*>(h);
    const int2* pair = pairb + (size_t)g * NE;
    const int* ro = row_off + g * (NN + 1);
    const float* bias = g ? biasB : biasA;
    float* out = outb + (size_t)g * NN * 64;

    int half = lane >> 5;
    int f = (lane & 31) * 2;
    int fb = (lane & 31) * 4;
    float di = dinv[(size_t)g * NN + node];
    int beg = ro[node];
    int end = ro[node + 1];

    float a0 = 0.f, a1 = 0.f;

    auto edge = [&](int2 p) {
        float c = __int_as_float(p.y);
        bf16x2 v = *reinterpret_cast<const bf16x2*>(hB + (((unsigned)p.x) >> 1) + fb);
        a0 = fmaf((float)v[0], c, a0); a1 = fmaf((float)v[1], c, a1);
    };

    int j = beg;
    for (; j + 7 < end; j += 8) {
        int2 p0 = pair[j + half], p1 = pair[j + 2 + half];
        int2 p2 = pair[j + 4 + half], p3 = pair[j + 6 + half];
        edge(p0); edge(p1); edge(p2); edge(p3);
    }
    for (; j + 1 < end; j += 2) edge(pair[j + half]);
    if (j < end && half == 0) edge(pair[j]);

    a0 += __shfl_xor(a0, 32);
    a1 += __shfl_xor(a1, 32);

    bf16x2 hv = *reinterpret_cast<const bf16x2*>(&h[(size_t)node * 64 + f]);
    float sc = di * di;
    a0 = fmaf((float)hv[0], sc, a0) + bias[f];
    a1 = fmaf((float)hv[1], sc, a1) + bias[f + 1];

    if (half == 0) {
        out[(size_t)node * 64 + f] = a0;
        out[(size_t)node * 64 + f + 1] = a1;
    }
}

extern "C" void kernel_launch(void* const* d_in, const int* in_sizes, int n_in,
                              void* d_out, int out_size, void* d_ws, size_t ws_size,
                              hipStream_t stream) {
    const float* x1 = (const float*)d_in[0];
    const int* ei1 = (const int*)d_in[1];
    const float* x2 = (const float*)d_in[2];
    const int* ei2 = (const int*)d_in[3];
    const float* W1_0 = (const float*)d_in[4];
    const float* b1_0 = (const float*)d_in[5];
    const float* W1_1 = (const float*)d_in[6];
    const float* b1_1 = (const float*)d_in[7];
    const float* W2_0 = (const float*)d_in[8];
    const float* b2_0 = (const float*)d_in[9];
    const float* W2_1 = (const float*)d_in[10];
    const float* b2_1 = (const float*)d_in[11];

    float* out = (float*)d_out;  // [2][NN][64] concatenated

    char* ws = (char*)d_ws;
    size_t off = 0;
    auto alloc = [&](size_t bytes) {
        size_t o = off;
        off = (off + bytes + 255) & ~(size_t)255;
        return o;
    };
    // h: live mega -> agg128. region2: stg (dead after binB2) then h2 (written by gemm_l2).
    bf16* h = (bf16*)(ws + alloc((size_t)2 * NN * 128 * 2));       // 25.6 MB
    size_t r2 = (size_t)2 * NB * CAP * 8;                          // 12.85 MB (>= h2's 12.8)
    char* region2 = ws + alloc(r2);
    int2* stg = (int2*)region2;
    bf16* h2 = (bf16*)region2;
    bf16* a = (bf16*)(ws + alloc((size_t)2 * NN * 128 * 2));       // 25.6 MB
    int2* pair = (int2*)(ws + alloc((size_t)2 * NE * 8));          // 9.6 MB
    int* row_off = (int*)(ws + alloc((size_t)2 * (NN + 1) * 4));
    float* dinv = (float*)(ws + alloc((size_t)2 * NN * 4));
    int* bucketcur = (int*)(ws + alloc((size_t)2 * NB * 4));
    bf16* wf0 = (bf16*)(ws + alloc((size_t)2 * 256 * 128 * 2));
    bf16* wf1 = (bf16*)(ws + alloc((size_t)2 * 128 * 64 * 2));

    const int* srcA = ei1, *dstA = ei1 + NE;
    const int* srcB = ei2, *dstB = ei2 + NE;

    k_wprep4<<<dim3(128, 5), 256, 0, stream>>>(W1_0, W2_0, W1_1, W2_1, wf0, wf1,
                                               bucketcur, row_off);
    k_mega<<<2 * NCH + 2 * GB, 256, 0, stream>>>(x1, x2, wf0, h,
                                                 srcA, dstA, srcB, dstB, bucketcur, stg);
    k_binB1<<<dim3(NB, 2), 256, 0, stream>>>(stg, bucketcur, row_off, dinv);
    k_binB2<<<dim3(NB, 2), 256, 0, stream>>>(stg, bucketcur, row_off, dinv, pair);

    agg128_2<<<(2 * NN) / 4, 256, 0, stream>>>(h, row_off, pair, dinv, b1_0, b2_0, a);
    gemm_l2<<<2 * GB, 256, 0, stream>>>(a, wf1, h2);
    agg64_2<<<(2 * NN) / 4, 256, 0, stream>>>(h2, row_off, pair, dinv, b1_1, b2_1, out);
}